// Round 6
// baseline (18210.321 us; speedup 1.0000x reference)
//
#include <hip/hip_runtime.h>
#include <hip/hip_bf16.h>
#include <cstdint>
#include <cstddef>

typedef __attribute__((ext_vector_type(8))) short bf16x8;
typedef __attribute__((ext_vector_type(4))) float f32x4;

#define DEV static __device__ __forceinline__

DEV float bf2f(uint16_t u){ union{uint32_t i; float f;} c; c.i = ((uint32_t)u) << 16; return c.f; }
DEV uint16_t f2bf(float f){ union{float f; uint32_t i;} c; c.f = f; uint32_t r = c.i + 0x7FFFu + ((c.i >> 16) & 1u); return (uint16_t)(r >> 16); }
DEV uint32_t cvtpk(float lo, float hi){
  uint32_t r;
  asm("v_cvt_pk_bf16_f32 %0, %1, %2" : "=v"(r) : "v"(lo), "v"(hi));
  return r;
}

DEV f32x4 mfma16(bf16x8 a, bf16x8 b, f32x4 c){
  return __builtin_amdgcn_mfma_f32_16x16x32_bf16(a, b, c, 0, 0, 0);
}

// ---------------------------------------------------------------------------
// Gate MLP: c[s] = mean_b sigmoid( silu(x[b,s,:]@W1^T + b1) @ W2^T + b2 )
// ---------------------------------------------------------------------------
__global__ __launch_bounds__(128) void nltm_coeff(
    const float* __restrict__ x,
    const float* __restrict__ aW1, const float* __restrict__ ab1,
    const float* __restrict__ aW2, const float* __restrict__ ab2,
    const float* __restrict__ tW1, const float* __restrict__ tb1,
    const float* __restrict__ tW2, const float* __restrict__ tb2,
    const float* __restrict__ eW1, const float* __restrict__ eb1,
    const float* __restrict__ eW2, const float* __restrict__ eb2,
    float* __restrict__ gates)
{
  const int s = blockIdx.x, z = blockIdx.y;
  const int b = threadIdx.x >> 4, ch = threadIdx.x & 15;
  const float* w1 = (z==0)?aW1:(z==1)?tW1:eW1;
  const float* c1 = (z==0)?ab1:(z==1)?tb1:eb1;
  const float* w2 = (z==0)?aW2:(z==1)?tW2:eW2;
  const float* c2 = (z==0)?ab2:(z==1)?tb2:eb2;
  const float4* xp = (const float4*)(x + ((size_t)(b << 10) + s)*512);
  const float4* wp = (const float4*)(w1 + ch*512);
  float dot = 0.f;
  #pragma unroll 4
  for (int i = 0; i < 128; ++i){
    float4 a = xp[i], c = wp[i];
    dot += a.x*c.x + a.y*c.y + a.z*c.z + a.w*c.w;
  }
  dot += c1[ch];
  const float sg = 1.f / (1.f + __expf(-dot));
  float v = dot * sg * w2[ch];
  v += __shfl_xor(v, 1, 64);
  v += __shfl_xor(v, 2, 64);
  v += __shfl_xor(v, 4, 64);
  v += __shfl_xor(v, 8, 64);
  if (ch == 0){
    const float cc = 1.f / (1.f + __expf(-(v + c2[0])));
    atomicAdd(gates + (z << 10) + s, cc * 0.125f);
  }
}

// ---------------------------------------------------------------------------
// f32 GEMM: pre[n,m] = sum_d x[n,d]*W[m,d]  (NT), bf16 output
// ---------------------------------------------------------------------------
__global__ __launch_bounds__(256) void nltm_gemm(
    const float* __restrict__ x, const float* __restrict__ Wk,
    const float* __restrict__ Wv, const float* __restrict__ Wq,
    uint16_t* __restrict__ preK, uint16_t* __restrict__ preV, uint16_t* __restrict__ preQ)
{
  __shared__ float As[16][132];
  __shared__ float Bs[16][132];
  const float* W = (blockIdx.z == 0) ? Wk : (blockIdx.z == 1) ? Wv : Wq;
  uint16_t* op  = (blockIdx.z == 0) ? preK : (blockIdx.z == 1) ? preV : preQ;
  const int tid = threadIdx.x;
  const int n0 = blockIdx.x << 7, m0 = blockIdx.y << 7;
  const int r = tid >> 1, cs = (tid & 1) << 3;
  const int ty = tid >> 4, tx = tid & 15;
  float acc[8][8];
  #pragma unroll
  for (int i = 0; i < 8; ++i)
    #pragma unroll
    for (int j = 0; j < 8; ++j) acc[i][j] = 0.f;

  for (int k0 = 0; k0 < 512; k0 += 16){
    float4 a0 = *(const float4*)(x + (size_t)(n0 + r)*512 + k0 + cs);
    float4 a1 = *(const float4*)(x + (size_t)(n0 + r)*512 + k0 + cs + 4);
    float4 b0 = *(const float4*)(W + (size_t)(m0 + r)*512 + k0 + cs);
    float4 b1 = *(const float4*)(W + (size_t)(m0 + r)*512 + k0 + cs + 4);
    __syncthreads();
    As[cs+0][r]=a0.x; As[cs+1][r]=a0.y; As[cs+2][r]=a0.z; As[cs+3][r]=a0.w;
    As[cs+4][r]=a1.x; As[cs+5][r]=a1.y; As[cs+6][r]=a1.z; As[cs+7][r]=a1.w;
    Bs[cs+0][r]=b0.x; Bs[cs+1][r]=b0.y; Bs[cs+2][r]=b0.z; Bs[cs+3][r]=b0.w;
    Bs[cs+4][r]=b1.x; Bs[cs+5][r]=b1.y; Bs[cs+6][r]=b1.z; Bs[cs+7][r]=b1.w;
    __syncthreads();
    #pragma unroll
    for (int kk = 0; kk < 16; ++kk){
      float4 av0 = *(const float4*)&As[kk][ty*8];
      float4 av1 = *(const float4*)&As[kk][ty*8+4];
      float4 bv0 = *(const float4*)&Bs[kk][tx*8];
      float4 bv1 = *(const float4*)&Bs[kk][tx*8+4];
      const float aa[8] = {av0.x,av0.y,av0.z,av0.w,av1.x,av1.y,av1.z,av1.w};
      const float bb[8] = {bv0.x,bv0.y,bv0.z,bv0.w,bv1.x,bv1.y,bv1.z,bv1.w};
      #pragma unroll
      for (int i = 0; i < 8; ++i)
        #pragma unroll
        for (int j = 0; j < 8; ++j)
          acc[i][j] = fmaf(aa[i], bb[j], acc[i][j]);
    }
  }
  #pragma unroll
  for (int i = 0; i < 8; ++i){
    const size_t n = (size_t)(n0 + ty*8 + i);
    uint4 v;
    v.x = (uint32_t)f2bf(acc[i][0]) | ((uint32_t)f2bf(acc[i][1]) << 16);
    v.y = (uint32_t)f2bf(acc[i][2]) | ((uint32_t)f2bf(acc[i][3]) << 16);
    v.z = (uint32_t)f2bf(acc[i][4]) | ((uint32_t)f2bf(acc[i][5]) << 16);
    v.w = (uint32_t)f2bf(acc[i][6]) | ((uint32_t)f2bf(acc[i][7]) << 16);
    *(uint4*)(op + n*512 + m0 + tx*8) = v;
  }
}

// ---------------------------------------------------------------------------
// depthwise conv (K=3, same) + optional LN.
// post  : [S][B][M] bf16, nullable ; postT : [S][M][B] bf16, nullable
// ---------------------------------------------------------------------------
__global__ __launch_bounds__(512) void nltm_conv(
    const uint16_t* __restrict__ pre,
    const float* __restrict__ w, const float* __restrict__ wb,
    const float* __restrict__ lng, const float* __restrict__ lnb, const int doLN,
    uint16_t* __restrict__ post, uint16_t* __restrict__ postT)
{
  const int b = blockIdx.x >> 10, s = blockIdx.x & 1023;
  const int m = threadIdx.x;
  const size_t base = ((size_t)(b << 10) + s)*512 + m;
  const float xm = (s > 0)    ? bf2f(pre[base - 512]) : 0.f;
  const float x0 = bf2f(pre[base]);
  const float xp = (s < 1023) ? bf2f(pre[base + 512]) : 0.f;
  float y = fmaf(w[m*3], xm, fmaf(w[m*3+1], x0, fmaf(w[m*3+2], xp, wb[m])));
  if (doLN){
    __shared__ float red[2][8];
    float s1 = y, s2 = y*y;
    #pragma unroll
    for (int o = 32; o > 0; o >>= 1){
      s1 += __shfl_xor(s1, o, 64);
      s2 += __shfl_xor(s2, o, 64);
    }
    if ((threadIdx.x & 63) == 0){ red[0][threadIdx.x>>6] = s1; red[1][threadIdx.x>>6] = s2; }
    __syncthreads();
    float t1 = 0.f, t2 = 0.f;
    #pragma unroll
    for (int i = 0; i < 8; ++i){ t1 += red[0][i]; t2 += red[1][i]; }
    const float mean = t1 * (1.f/512.f);
    const float var  = t2 * (1.f/512.f) - mean*mean;
    y = (y - mean) * rsqrtf(var + 1e-5f) * lng[m] + lnb[m];
  }
  const uint16_t yb = f2bf(y);
  if (post)  post[((size_t)(s << 3) + b)*512 + m] = yb;
  if (postT) postT[(((size_t)s << 9) + m)*8 + b] = yb;
}

// ---------------------------------------------------------------------------
// Sequential scan: 1 block, 512 threads (8 waves), 1024 steps, 4 barriers/step.
// A': 2 waves, K=512 chained MFMAs (fused silu) -> HQK/HKST/SILP
// B : 8 waves, joint [y;ck] (K=32), y stores, g_out (GOT + natural rows)
// C': waves 0-1 gpre chains (uses W2T(t)); ALL waves GW2 nat+transposed MFMAs
//     (reused frags) updating both f32 master copies; no W2 LDS writes yet
// D : GW1 MFMAs + W1L/W2T/W2N packed writes from masters + biases + restage
// Three f32 master sets: w1m (h-row major), w2a ([m][h] m-packed per h -> W2T),
// w2t ([m][h] h-packed per m -> W2N). GW2^T = mfma(hkF,gof) is bit-identical
// to GW2 = mfma(gof,hkF) elementwise => both copies stay bit-identical.
// LDS: W1L[32][1040]@0  W2N[512][64]swz@33280  W2T[32][1040]@66048
//      QKL[16][1024]swz@99328 (rows 8-15 k -> g_out natural after B)
//      VT[512][16]@115712 KT[512][16]@123904 GOT[512][16]@132096
//      HQK[16][64]@140288 HKST[32][16]@141312 SILP[32][64]@141824
//      GPT[32][16]@143872 b1@144512 b2@144640 ; total 146688
// ---------------------------------------------------------------------------
__global__ __launch_bounds__(512, 2) void nltm_scan(
    const float* __restrict__ W1g, const float* __restrict__ b1g,
    const float* __restrict__ W2g, const float* __restrict__ b2g,
    const float* __restrict__ gates,
    const uint16_t* __restrict__ kN, const uint16_t* __restrict__ qN,
    const uint16_t* __restrict__ kT, const uint16_t* __restrict__ vT,
    float* __restrict__ out)
{
  constexpr uint32_t W1Lo=0, W2No=33280, W2To=66048, QKLo=99328, VTo=115712,
                     KTo=123904, GOTo=132096, HQKo=140288, HKSTo=141312,
                     SILPo=141824, GPTo=143872, B1o=144512, B2o=144640;
  __shared__ __align__(16) char smem[146688];
  const int tid = threadIdx.x;
  const int lane = tid & 63;
  const int wid = tid >> 6;        // 0..7, owns m in [wid*64, wid*64+64)
  const int rb = lane & 15;
  const int kg = lane >> 4;        // 0..3

  float* b1L = (float*)(smem + B1o);
  float* b2L = (float*)(smem + B2o);

  // ---- f32 master state ----
  float w1m[8][4], sm1[8][4], w2a[8][4], sma[8][4], w2t[8][4], smt[8][4];
  #pragma unroll
  for (int i = 0; i < 8; ++i){
    const int tt = i >> 1, ht = i & 1;
    const int mA = (wid*4 + tt)*16;
    #pragma unroll
    for (int j = 0; j < 4; ++j){
      const int h1 = ht*16 + rb, m1 = mA + kg*4 + j;
      w1m[i][j] = W1g[h1*512 + m1];  sm1[i][j] = 0.f;
      w2a[i][j] = W2g[m1*32 + h1];   sma[i][j] = 0.f;
      const int h2 = ht*16 + kg*4 + j, m2 = mA + rb;
      w2t[i][j] = W2g[m2*32 + h2];   smt[i][j] = 0.f;
    }
  }
  float b2m = b2g[tid], smb2 = 0.f;
  float b1m = (tid < 32) ? b1g[tid] : 0.f, smb1 = 0.f;

  // ---- LDS weights init ----
  for (int idx = tid; idx < 16384; idx += 512){
    const int h = idx >> 9, m = idx & 511;
    *(uint16_t*)(smem + W1Lo + h*1040 + m*2) = f2bf(W1g[idx]);          // idx=h*512+m
    const int m2 = idx >> 5, h2 = idx & 31;
    const float w2v = W2g[idx];                                          // idx=m2*32+h2
    *(uint16_t*)(smem + W2No + m2*64 + (((h2>>3)^(m2&3))<<4) + ((h2&7)<<1)) = f2bf(w2v);
    *(uint16_t*)(smem + W2To + h2*1040 + m2*2) = f2bf(w2v);
  }
  if (tid < 32) b1L[tid] = b1g[tid];
  b2L[tid] = b2g[tid];

  // ---- stage step 0 ----
  {
    const int sb = tid >> 6, g64 = tid & 63;
    const uint32_t swz = (uint32_t)((g64 ^ (sb & 7)) << 4);
    *(uint4*)(smem + QKLo + sb*1024 + swz)       = *(const uint4*)(qN + tid*8);
    *(uint4*)(smem + QKLo + (8+sb)*1024 + swz)   = *(const uint4*)(kN + tid*8);
    *(uint4*)(smem + KTo + tid*16) = *(const uint4*)(kT + tid*8);
    *(uint4*)(smem + VTo + tid*16) = *(const uint4*)(vT + tid*8);
  }
  __syncthreads();

  const f32x4 cz = {0.f, 0.f, 0.f, 0.f};
  const bf16x8 zf = {0,0,0,0,0,0,0,0};

  for (int t = 0; t < 1024; ++t){
    // ---- prefetch next step (consumed in D restage) ----
    const int tn = (t < 1023) ? (t + 1) : 1023;
    uint4 pfq  = *(const uint4*)(qN + (size_t)tn*4096 + tid*8);
    uint4 pfk  = *(const uint4*)(kN + (size_t)tn*4096 + tid*8);
    uint4 ktpf = *(const uint4*)(kT + (size_t)tn*4096 + tid*8);
    uint4 vtpf = *(const uint4*)(vT + (size_t)tn*4096 + tid*8);
    const float a_t = gates[t], th_t = gates[1024 + t], e_t = gates[2048 + t];
    const float oma = 1.f - a_t;

    // ============ A': [hq;hk] = [q;k]@W1^T, K=512 chains, 2 waves ============
    if (wid < 2){
      const int ht = wid;
      const uint32_t w1row = W1Lo + (uint32_t)(ht*16 + rb)*1040;
      f32x4 a0 = cz, a1 = cz;
      #pragma unroll
      for (int c = 0; c < 16; c += 2){
        bf16x8 av0 = *(const bf16x8*)(smem + QKLo + rb*1024 + ((((c  )*4 + kg) ^ (rb&7)) << 4));
        bf16x8 bv0 = *(const bf16x8*)(smem + w1row + c*64 + kg*16);
        a0 = mfma16(av0, bv0, a0);
        bf16x8 av1 = *(const bf16x8*)(smem + QKLo + rb*1024 + ((((c+1)*4 + kg) ^ (rb&7)) << 4));
        bf16x8 bv1 = *(const bf16x8*)(smem + w1row + (c+1)*64 + kg*16);
        a1 = mfma16(av1, bv1, a1);
      }
      f32x4 acc = a0 + a1;
      const int h = ht*16 + rb;
      const float b1v = b1L[h];
      float hs[4], sd[4];
      #pragma unroll
      for (int j = 0; j < 4; ++j){
        const float z = acc[j] + b1v;
        const float sg = 1.f / (1.f + __expf(-z));
        hs[j] = z * sg;
        sd[j] = sg * (1.f + z * (1.f - sg));
      }
      #pragma unroll
      for (int j = 0; j < 4; ++j)
        *(uint16_t*)(smem + HQKo + (kg*4 + j)*64 + h*2) = f2bf(hs[j]);
      if (kg >= 2){
        uint2 hv; hv.x = cvtpk(hs[0], hs[1]); hv.y = cvtpk(hs[2], hs[3]);
        *(uint2*)(smem + HKSTo + h*16 + (kg-2)*8) = hv;
        f32x4 sv = {sd[0], sd[1], sd[2], sd[3]};
        *(f32x4*)(smem + SILPo + h*64 + (kg-2)*16) = sv;
      }
    }
    __syncthreads();

    // ============ B: [y;ck] = [hq;hk]@W2^T ; y store; g_out ============
    {
      bf16x8 aF = *(const bf16x8*)(smem + HQKo + rb*64 + kg*16);
      #pragma unroll
      for (int u = 0; u < 4; ++u){
        const int mcol = (wid*4 + u)*16 + rb;
        bf16x8 bw = *(const bf16x8*)(smem + W2No + mcol*64 + ((kg ^ (mcol&3)) << 4));
        f32x4 c = mfma16(aF, bw, cz);
        const float b2v = b2L[mcol];
        if (kg < 2){
          #pragma unroll
          for (int j = 0; j < 4; ++j)
            out[(((size_t)(kg*4 + j) << 10) + t)*512 + mcol] = c[j] + b2v;
        } else {
          uint2 vt = *(const uint2*)(smem + VTo + mcol*16 + (kg-2)*8);
          float g0 = (c[0] + b2v - bf2f((uint16_t)vt.x))       * 4.8828125e-4f;
          float g1 = (c[1] + b2v - bf2f((uint16_t)(vt.x>>16))) * 4.8828125e-4f;
          float g2 = (c[2] + b2v - bf2f((uint16_t)vt.y))       * 4.8828125e-4f;
          float g3 = (c[3] + b2v - bf2f((uint16_t)(vt.y>>16))) * 4.8828125e-4f;
          uint2 gp; gp.x = cvtpk(g0, g1); gp.y = cvtpk(g2, g3);
          *(uint2*)(smem + GOTo + mcol*16 + (kg-2)*8) = gp;
          #pragma unroll
          for (int j = 0; j < 4; ++j){
            const int b = kg*4 + j - 8;
            const uint16_t gb = (uint16_t)((j & 1) ? ((j < 2 ? gp.x : gp.y) >> 16)
                                                   : (j < 2 ? gp.x : gp.y));
            *(uint16_t*)(smem + QKLo + (8+b)*1024 + (((mcol>>3) ^ (b&7)) << 4) + ((mcol&7) << 1)) = gb;
          }
        }
      }
    }
    __syncthreads();

    // ============ C': gpre chains (waves 0-1) + GW2 nat/T (all waves) ============
    {
      if (wid < 2){
        const int ht = wid;
        const uint32_t w2row = W2To + (uint32_t)(ht*16 + rb)*1040;
        f32x4 a0 = cz, a1 = cz;
        #pragma unroll
        for (int c = 0; c < 16; c += 2){
          bf16x8 av0 = (rb < 8) ? *(const bf16x8*)(smem + QKLo + (8+rb)*1024 + ((((c  )*4 + kg) ^ (rb&7)) << 4)) : zf;
          bf16x8 bv0 = *(const bf16x8*)(smem + w2row + c*64 + kg*16);
          a0 = mfma16(av0, bv0, a0);
          bf16x8 av1 = (rb < 8) ? *(const bf16x8*)(smem + QKLo + (8+rb)*1024 + ((((c+1)*4 + kg) ^ (rb&7)) << 4)) : zf;
          bf16x8 bv1 = *(const bf16x8*)(smem + w2row + (c+1)*64 + kg*16);
          a1 = mfma16(av1, bv1, a1);
        }
        f32x4 acc = a0 + a1;
        if (kg < 2){
          const int h = ht*16 + rb;
          f32x4 sp = *(const f32x4*)(smem + SILPo + h*64 + kg*16);
          uint2 w; w.x = cvtpk(acc[0]*sp[0], acc[1]*sp[1]);
                   w.y = cvtpk(acc[2]*sp[2], acc[3]*sp[3]);
          *(uint2*)(smem + GPTo + h*16 + kg*8) = w;
        }
      }
      // GW2 (natural + transposed) on all waves; masters updated, writes deferred
      bf16x8 hkF0 = (kg == 0) ? *(const bf16x8*)(smem + HKSTo + rb*16)        : zf;
      bf16x8 hkF1 = (kg == 0) ? *(const bf16x8*)(smem + HKSTo + (16+rb)*16)   : zf;
      #pragma unroll
      for (int tt = 0; tt < 4; ++tt){
        const int mA = (wid*4 + tt)*16;
        bf16x8 gof = (kg == 0) ? *(const bf16x8*)(smem + GOTo + (mA + rb)*16) : zf;
        #pragma unroll
        for (int ht = 0; ht < 2; ++ht){
          const int i = tt*2 + ht;
          f32x4 g2  = mfma16(gof, ht ? hkF1 : hkF0, cz);  // (m=mA+kg*4+j, h=ht*16+rb)
          f32x4 g2t = mfma16(ht ? hkF1 : hkF0, gof, cz);  // (h=ht*16+kg*4+j, m=mA+rb)
          #pragma unroll
          for (int j = 0; j < 4; ++j){
            sma[i][j] = e_t*sma[i][j] - th_t*g2[j];
            w2a[i][j] = oma*w2a[i][j] + sma[i][j];
            smt[i][j] = e_t*smt[i][j] - th_t*g2t[j];
            w2t[i][j] = oma*w2t[i][j] + smt[i][j];
          }
        }
      }
    }
    __syncthreads();

    // ============ D: GW1 + weight/bias writes + restage ============
    {
      bf16x8 gpF0 = (kg == 0) ? *(const bf16x8*)(smem + GPTo + rb*16)      : zf;
      bf16x8 gpF1 = (kg == 0) ? *(const bf16x8*)(smem + GPTo + (16+rb)*16) : zf;
      #pragma unroll
      for (int tt = 0; tt < 4; ++tt){
        const int mA = (wid*4 + tt)*16;
        bf16x8 ktf = (kg == 0) ? *(const bf16x8*)(smem + KTo + (mA + rb)*16) : zf;
        #pragma unroll
        for (int ht = 0; ht < 2; ++ht){
          const int i = tt*2 + ht;
          f32x4 g1 = mfma16(ktf, ht ? gpF1 : gpF0, cz);   // (m=mA+kg*4+j, h=ht*16+rb)
          #pragma unroll
          for (int j = 0; j < 4; ++j){
            sm1[i][j] = e_t*sm1[i][j] - th_t*g1[j];
            w1m[i][j] = oma*w1m[i][j] + sm1[i][j];
          }
          uint2 u1; u1.x = cvtpk(w1m[i][0], w1m[i][1]); u1.y = cvtpk(w1m[i][2], w1m[i][3]);
          *(uint2*)(smem + W1Lo + (ht*16 + rb)*1040 + (mA + kg*4)*2) = u1;
          uint2 u2; u2.x = cvtpk(w2a[i][0], w2a[i][1]); u2.y = cvtpk(w2a[i][2], w2a[i][3]);
          *(uint2*)(smem + W2To + (ht*16 + rb)*1040 + (mA + kg*4)*2) = u2;
          uint2 u3; u3.x = cvtpk(w2t[i][0], w2t[i][1]); u3.y = cvtpk(w2t[i][2], w2t[i][3]);
          *(uint2*)(smem + W2No + (mA + rb)*64 + ((((ht<<1)+(kg>>1)) ^ (rb&3)) << 4) + ((kg&1) << 3)) = u3;
        }
      }
      // bias updates
      {
        uint4 gv = *(const uint4*)(smem + GOTo + tid*16);
        float gb2 = bf2f((uint16_t)gv.x) + bf2f((uint16_t)(gv.x>>16))
                  + bf2f((uint16_t)gv.y) + bf2f((uint16_t)(gv.y>>16))
                  + bf2f((uint16_t)gv.z) + bf2f((uint16_t)(gv.z>>16))
                  + bf2f((uint16_t)gv.w) + bf2f((uint16_t)(gv.w>>16));
        smb2 = e_t*smb2 - th_t*gb2;
        b2m = oma*b2m + smb2;
        b2L[tid] = b2m;
      }
      if (tid < 32){
        uint4 gv = *(const uint4*)(smem + GPTo + tid*16);
        float gb1 = bf2f((uint16_t)gv.x) + bf2f((uint16_t)(gv.x>>16))
                  + bf2f((uint16_t)gv.y) + bf2f((uint16_t)(gv.y>>16))
                  + bf2f((uint16_t)gv.z) + bf2f((uint16_t)(gv.z>>16))
                  + bf2f((uint16_t)gv.w) + bf2f((uint16_t)(gv.w>>16));
        smb1 = e_t*smb1 - th_t*gb1;
        b1m = oma*b1m + smb1;
        b1L[tid] = b1m;
      }
      // restage next step
      {
        const int sb = tid >> 6, g64 = tid & 63;
        const uint32_t swz = (uint32_t)((g64 ^ (sb & 7)) << 4);
        *(uint4*)(smem + QKLo + sb*1024 + swz)     = pfq;
        *(uint4*)(smem + QKLo + (8+sb)*1024 + swz) = pfk;
        *(uint4*)(smem + KTo + tid*16) = ktpf;
        *(uint4*)(smem + VTo + tid*16) = vtpf;
      }
    }
    __syncthreads();
  }
}

// ---------------------------------------------------------------------------
extern "C" void kernel_launch(void* const* d_in, const int* in_sizes, int n_in,
                              void* d_out, int out_size, void* d_ws, size_t ws_size,
                              hipStream_t stream)
{
  const float* x   = (const float*)d_in[0];
  const float* Wk  = (const float*)d_in[1];
  const float* Wv  = (const float*)d_in[2];
  const float* Wq  = (const float*)d_in[3];
  const float* ckw = (const float*)d_in[4];
  const float* ckb = (const float*)d_in[5];
  const float* cvw = (const float*)d_in[6];
  const float* cvb = (const float*)d_in[7];
  const float* cqw = (const float*)d_in[8];
  const float* cqb = (const float*)d_in[9];
  const float* lng = (const float*)d_in[10];
  const float* lnb = (const float*)d_in[11];
  const float* W1g = (const float*)d_in[12];
  const float* b1g = (const float*)d_in[13];
  const float* W2g = (const float*)d_in[14];
  const float* b2g = (const float*)d_in[15];
  const float* aW1 = (const float*)d_in[16];
  const float* ab1 = (const float*)d_in[17];
  const float* aW2 = (const float*)d_in[18];
  const float* ab2 = (const float*)d_in[19];
  const float* tW1 = (const float*)d_in[20];
  const float* tb1 = (const float*)d_in[21];
  const float* tW2 = (const float*)d_in[22];
  const float* tb2 = (const float*)d_in[23];
  const float* eW1 = (const float*)d_in[24];
  const float* eb1 = (const float*)d_in[25];
  const float* eW2 = (const float*)d_in[26];
  const float* eb2 = (const float*)d_in[27];

  char* ws = (char*)d_ws;
  float* gates = (float*)ws;                       // 3*1024 f32
  uint16_t* preK   = (uint16_t*)(ws + 16384);      // 6 x 8MB bf16
  uint16_t* preV   = preK + 4194304;               // reused as postKT after convV
  uint16_t* preQ   = preV + 4194304;
  uint16_t* postK  = preQ + 4194304;               // [S][B][M]
  uint16_t* postQ  = postK + 4194304;              // [S][B][M]
  uint16_t* postVT = postQ + 4194304;              // [S][M][B]
  uint16_t* postKT = preV;                         // [S][M][B] (overlay)

  hipMemsetAsync(gates, 0, 3*1024*sizeof(float), stream);
  nltm_coeff<<<dim3(1024,3), 128, 0, stream>>>(x, aW1,ab1,aW2,ab2, tW1,tb1,tW2,tb2,
                                               eW1,eb1,eW2,eb2, gates);
  nltm_gemm<<<dim3(64,4,3), 256, 0, stream>>>(x, Wk, Wv, Wq, preK, preV, preQ);
  // convV first (frees preV slot), then convK writes postKT into it
  nltm_conv<<<dim3(8192), 512, 0, stream>>>(preV, cvw, cvb, lng, lnb, 0, nullptr, postVT);
  nltm_conv<<<dim3(8192), 512, 0, stream>>>(preK, ckw, ckb, lng, lnb, 1, postK, postKT);
  nltm_conv<<<dim3(8192), 512, 0, stream>>>(preQ, cqw, cqb, lng, lnb, 1, postQ, nullptr);
  nltm_scan<<<dim3(1), dim3(512), 0, stream>>>(W1g, b1g, W2g, b2g, gates,
                                               postK, postQ, postKT, postVT,
                                               (float*)d_out);
}

// Round 7
// 10419.382 us; speedup vs baseline: 1.7477x; 1.7477x over previous
//
#include <hip/hip_runtime.h>
#include <hip/hip_bf16.h>
#include <cstdint>
#include <cstddef>

typedef __attribute__((ext_vector_type(8))) short bf16x8;
typedef __attribute__((ext_vector_type(4))) float f32x4;

#define DEV static __device__ __forceinline__

DEV float bf2f(uint16_t u){ union{uint32_t i; float f;} c; c.i = ((uint32_t)u) << 16; return c.f; }
DEV uint16_t f2bf(float f){ union{float f; uint32_t i;} c; c.f = f; uint32_t r = c.i + 0x7FFFu + ((c.i >> 16) & 1u); return (uint16_t)(r >> 16); }
DEV uint32_t cvtpk(float lo, float hi){
  uint32_t r;
  asm("v_cvt_pk_bf16_f32 %0, %1, %2" : "=v"(r) : "v"(lo), "v"(hi));
  return r;
}

DEV f32x4 mfma16(bf16x8 a, bf16x8 b, f32x4 c){
  return __builtin_amdgcn_mfma_f32_16x16x32_bf16(a, b, c, 0, 0, 0);
}

// Relaxed barrier: wait only on LDS/SMEM (lgkmcnt), leave vmcnt uncounted so
// per-step global prefetch loads and out-stores stay in flight across phases.
// sched_barrier(0) fences prevent hipcc from hoisting/sinking memory ops past
// the inline-asm waitcnt (guide rule #18).
DEV void bar(){
  asm volatile("" ::: "memory");
  __builtin_amdgcn_sched_barrier(0);
  asm volatile("s_waitcnt lgkmcnt(0)" ::: "memory");
  __builtin_amdgcn_s_barrier();
  __builtin_amdgcn_sched_barrier(0);
  asm volatile("" ::: "memory");
}

// ---------------------------------------------------------------------------
// Gate MLP: c[s] = mean_b sigmoid( silu(x[b,s,:]@W1^T + b1) @ W2^T + b2 )
// ---------------------------------------------------------------------------
__global__ __launch_bounds__(128) void nltm_coeff(
    const float* __restrict__ x,
    const float* __restrict__ aW1, const float* __restrict__ ab1,
    const float* __restrict__ aW2, const float* __restrict__ ab2,
    const float* __restrict__ tW1, const float* __restrict__ tb1,
    const float* __restrict__ tW2, const float* __restrict__ tb2,
    const float* __restrict__ eW1, const float* __restrict__ eb1,
    const float* __restrict__ eW2, const float* __restrict__ eb2,
    float* __restrict__ gates)
{
  const int s = blockIdx.x, z = blockIdx.y;
  const int b = threadIdx.x >> 4, ch = threadIdx.x & 15;
  const float* w1 = (z==0)?aW1:(z==1)?tW1:eW1;
  const float* c1 = (z==0)?ab1:(z==1)?tb1:eb1;
  const float* w2 = (z==0)?aW2:(z==1)?tW2:eW2;
  const float* c2 = (z==0)?ab2:(z==1)?tb2:eb2;
  const float4* xp = (const float4*)(x + ((size_t)(b << 10) + s)*512);
  const float4* wp = (const float4*)(w1 + ch*512);
  float dot = 0.f;
  #pragma unroll 4
  for (int i = 0; i < 128; ++i){
    float4 a = xp[i], c = wp[i];
    dot += a.x*c.x + a.y*c.y + a.z*c.z + a.w*c.w;
  }
  dot += c1[ch];
  const float sg = 1.f / (1.f + __expf(-dot));
  float v = dot * sg * w2[ch];
  v += __shfl_xor(v, 1, 64);
  v += __shfl_xor(v, 2, 64);
  v += __shfl_xor(v, 4, 64);
  v += __shfl_xor(v, 8, 64);
  if (ch == 0){
    const float cc = 1.f / (1.f + __expf(-(v + c2[0])));
    atomicAdd(gates + (z << 10) + s, cc * 0.125f);
  }
}

// ---------------------------------------------------------------------------
// f32 GEMM: pre[n,m] = sum_d x[n,d]*W[m,d]  (NT), bf16 output
// ---------------------------------------------------------------------------
__global__ __launch_bounds__(256) void nltm_gemm(
    const float* __restrict__ x, const float* __restrict__ Wk,
    const float* __restrict__ Wv, const float* __restrict__ Wq,
    uint16_t* __restrict__ preK, uint16_t* __restrict__ preV, uint16_t* __restrict__ preQ)
{
  __shared__ float As[16][132];
  __shared__ float Bs[16][132];
  const float* W = (blockIdx.z == 0) ? Wk : (blockIdx.z == 1) ? Wv : Wq;
  uint16_t* op  = (blockIdx.z == 0) ? preK : (blockIdx.z == 1) ? preV : preQ;
  const int tid = threadIdx.x;
  const int n0 = blockIdx.x << 7, m0 = blockIdx.y << 7;
  const int r = tid >> 1, cs = (tid & 1) << 3;
  const int ty = tid >> 4, tx = tid & 15;
  float acc[8][8];
  #pragma unroll
  for (int i = 0; i < 8; ++i)
    #pragma unroll
    for (int j = 0; j < 8; ++j) acc[i][j] = 0.f;

  for (int k0 = 0; k0 < 512; k0 += 16){
    float4 a0 = *(const float4*)(x + (size_t)(n0 + r)*512 + k0 + cs);
    float4 a1 = *(const float4*)(x + (size_t)(n0 + r)*512 + k0 + cs + 4);
    float4 b0 = *(const float4*)(W + (size_t)(m0 + r)*512 + k0 + cs);
    float4 b1 = *(const float4*)(W + (size_t)(m0 + r)*512 + k0 + cs + 4);
    __syncthreads();
    As[cs+0][r]=a0.x; As[cs+1][r]=a0.y; As[cs+2][r]=a0.z; As[cs+3][r]=a0.w;
    As[cs+4][r]=a1.x; As[cs+5][r]=a1.y; As[cs+6][r]=a1.z; As[cs+7][r]=a1.w;
    Bs[cs+0][r]=b0.x; Bs[cs+1][r]=b0.y; Bs[cs+2][r]=b0.z; Bs[cs+3][r]=b0.w;
    Bs[cs+4][r]=b1.x; Bs[cs+5][r]=b1.y; Bs[cs+6][r]=b1.z; Bs[cs+7][r]=b1.w;
    __syncthreads();
    #pragma unroll
    for (int kk = 0; kk < 16; ++kk){
      float4 av0 = *(const float4*)&As[kk][ty*8];
      float4 av1 = *(const float4*)&As[kk][ty*8+4];
      float4 bv0 = *(const float4*)&Bs[kk][tx*8];
      float4 bv1 = *(const float4*)&Bs[kk][tx*8+4];
      const float aa[8] = {av0.x,av0.y,av0.z,av0.w,av1.x,av1.y,av1.z,av1.w};
      const float bb[8] = {bv0.x,bv0.y,bv0.z,bv0.w,bv1.x,bv1.y,bv1.z,bv1.w};
      #pragma unroll
      for (int i = 0; i < 8; ++i)
        #pragma unroll
        for (int j = 0; j < 8; ++j)
          acc[i][j] = fmaf(aa[i], bb[j], acc[i][j]);
    }
  }
  #pragma unroll
  for (int i = 0; i < 8; ++i){
    const size_t n = (size_t)(n0 + ty*8 + i);
    uint4 v;
    v.x = (uint32_t)f2bf(acc[i][0]) | ((uint32_t)f2bf(acc[i][1]) << 16);
    v.y = (uint32_t)f2bf(acc[i][2]) | ((uint32_t)f2bf(acc[i][3]) << 16);
    v.z = (uint32_t)f2bf(acc[i][4]) | ((uint32_t)f2bf(acc[i][5]) << 16);
    v.w = (uint32_t)f2bf(acc[i][6]) | ((uint32_t)f2bf(acc[i][7]) << 16);
    *(uint4*)(op + n*512 + m0 + tx*8) = v;
  }
}

// ---------------------------------------------------------------------------
// depthwise conv (K=3, same) + optional LN.
// post  : [S][B][M] bf16, nullable ; postT : [S][M][B] bf16, nullable
// ---------------------------------------------------------------------------
__global__ __launch_bounds__(512) void nltm_conv(
    const uint16_t* __restrict__ pre,
    const float* __restrict__ w, const float* __restrict__ wb,
    const float* __restrict__ lng, const float* __restrict__ lnb, const int doLN,
    uint16_t* __restrict__ post, uint16_t* __restrict__ postT)
{
  const int b = blockIdx.x >> 10, s = blockIdx.x & 1023;
  const int m = threadIdx.x;
  const size_t base = ((size_t)(b << 10) + s)*512 + m;
  const float xm = (s > 0)    ? bf2f(pre[base - 512]) : 0.f;
  const float x0 = bf2f(pre[base]);
  const float xp = (s < 1023) ? bf2f(pre[base + 512]) : 0.f;
  float y = fmaf(w[m*3], xm, fmaf(w[m*3+1], x0, fmaf(w[m*3+2], xp, wb[m])));
  if (doLN){
    __shared__ float red[2][8];
    float s1 = y, s2 = y*y;
    #pragma unroll
    for (int o = 32; o > 0; o >>= 1){
      s1 += __shfl_xor(s1, o, 64);
      s2 += __shfl_xor(s2, o, 64);
    }
    if ((threadIdx.x & 63) == 0){ red[0][threadIdx.x>>6] = s1; red[1][threadIdx.x>>6] = s2; }
    __syncthreads();
    float t1 = 0.f, t2 = 0.f;
    #pragma unroll
    for (int i = 0; i < 8; ++i){ t1 += red[0][i]; t2 += red[1][i]; }
    const float mean = t1 * (1.f/512.f);
    const float var  = t2 * (1.f/512.f) - mean*mean;
    y = (y - mean) * rsqrtf(var + 1e-5f) * lng[m] + lnb[m];
  }
  const uint16_t yb = f2bf(y);
  if (post)  post[((size_t)(s << 3) + b)*512 + m] = yb;
  if (postT) postT[(((size_t)s << 9) + m)*8 + b] = yb;
}

// ---------------------------------------------------------------------------
// Sequential scan: 1 block, 1024 threads (16 waves), 1024 steps.
// Round-4 structure (best measured: 10.0 ms) + relaxed lgkm-only barriers.
// LDS map: see offsets below (identical to round 4).
// ---------------------------------------------------------------------------
__global__ __launch_bounds__(1024) void nltm_scan(
    const float* __restrict__ W1g, const float* __restrict__ b1g,
    const float* __restrict__ W2g, const float* __restrict__ b2g,
    const float* __restrict__ gates,
    const uint16_t* __restrict__ kN, const uint16_t* __restrict__ qN,
    const uint16_t* __restrict__ kT, const uint16_t* __restrict__ vT,
    float* __restrict__ out)
{
  constexpr uint32_t W1Lo=0, W2No=33280, W2To=66048, QKLo=99328, VTo=115712,
                     KTo=123904, GOTo=132096, HQKo=140288, HKSTo=141312,
                     SILPo=141824, GPTo=143872, SCRo=144384, B1o=160768, B2o=160896;
  __shared__ __align__(16) char smem[162944];
  const int tid = threadIdx.x;
  const int lane = tid & 63;
  const int wid = tid >> 6;        // 0..15
  const int rb = lane & 15;
  const int kg = lane >> 4;        // 0..3

  float* b1L = (float*)(smem + B1o);
  float* b2L = (float*)(smem + B2o);

  // ---- master state (f32, registers): wave wid owns m in [wid*32, wid*32+32) ----
  float w1m[4][4], sm1[4][4], w2a[4][4], sma[4][4];
  #pragma unroll
  for (int i = 0; i < 4; ++i){
    const int tt = i >> 1, ht = i & 1;
    const int mA = (wid*2 + tt)*16;
    #pragma unroll
    for (int j = 0; j < 4; ++j){
      const int h1 = ht*16 + rb, m1 = mA + kg*4 + j;
      w1m[i][j] = W1g[h1*512 + m1];  sm1[i][j] = 0.f;
      w2a[i][j] = W2g[m1*32 + h1];   sma[i][j] = 0.f;
    }
  }
  float b2m = (tid < 512) ? b2g[tid] : 0.f, smb2 = 0.f;
  float b1m = (tid < 32) ? b1g[tid] : 0.f, smb1 = 0.f;

  // ---- LDS weights init ----
  for (int idx = tid; idx < 16384; idx += 1024){
    const int h = idx >> 9, m = idx & 511;
    *(uint16_t*)(smem + W1Lo + h*1040 + m*2) = f2bf(W1g[idx]);          // idx=h*512+m
    const int m2 = idx >> 5, h2 = idx & 31;
    const float w2v = W2g[idx];                                          // idx=m2*32+h2
    *(uint16_t*)(smem + W2No + m2*64 + (((h2>>3)^(m2&3))<<4) + ((h2&7)<<1)) = f2bf(w2v);
    *(uint16_t*)(smem + W2To + h2*1040 + m2*2) = f2bf(w2v);
  }
  if (tid < 32) b1L[tid] = b1g[tid];
  if (tid < 512) b2L[tid] = b2g[tid];

  // ---- stage step 0 ----
  {
    const int b = tid >> 7, m4 = (tid & 127) << 2;
    const uint32_t swz = (((m4>>3) ^ (b&7))<<4) + ((m4&7)<<1);
    *(uint2*)(smem + QKLo + b*1024 + swz)       = *(const uint2*)(qN + tid*4);
    *(uint2*)(smem + QKLo + (8+b)*1024 + swz)   = *(const uint2*)(kN + tid*4);
    if (tid < 512) *(uint4*)(smem + KTo + tid*16) = *(const uint4*)(kT + tid*8);
    else           *(uint4*)(smem + VTo + (tid-512)*16) = *(const uint4*)(vT + (tid-512)*8);
  }
  __syncthreads();

  const f32x4 cz = {0.f, 0.f, 0.f, 0.f};
  const bf16x8 zf = {0,0,0,0,0,0,0,0};
  const int ht_ = wid & 1, ks_ = wid >> 1;

  for (int t = 0; t < 1024; ++t){
    // ---- prefetch next step (registers; consumed in phase D restage) ----
    const int tn = (t < 1023) ? (t + 1) : 1023;
    uint2 pfq = *(const uint2*)(qN + (size_t)tn*4096 + tid*4);
    uint2 pfk = *(const uint2*)(kN + (size_t)tn*4096 + tid*4);
    uint4 pf4;
    if (lane < 32) pf4 = *(const uint4*)(kT + (size_t)tn*4096 + (wid*32 + lane)*8);
    else           pf4 = *(const uint4*)(vT + (size_t)tn*4096 + (wid*32 + lane - 32)*8);
    const float a_t = gates[t], th_t = gates[1024 + t], e_t = gates[2048 + t];
    const float oma = 1.f - a_t;

    // ============ phase A: [hq;hk] = [q;k] @ W1^T  (16 waves: ht x ks8) ============
    {
      const uint32_t w1row = W1Lo + (uint32_t)(ht_*16 + rb)*1040;
      f32x4 acc = cz;
      #pragma unroll
      for (int u = 0; u < 2; ++u){
        const int c32 = ks_*2 + u;
        bf16x8 av = *(const bf16x8*)(smem + QKLo + rb*1024 + (((c32*4 + kg) ^ (rb&7)) << 4));
        bf16x8 bv = *(const bf16x8*)(smem + w1row + c32*64 + kg*16);
        acc = mfma16(av, bv, acc);
      }
      *(f32x4*)(smem + SCRo + ((wid*64 + lane) << 4)) = acc;
    }
    bar();

    // ============ Ared: reduce + silu/silu' (waves 0-1) ============
    if (wid < 2){
      const int ht = wid;
      f32x4 s = cz;
      #pragma unroll
      for (int ks = 0; ks < 8; ++ks)
        s += *(const f32x4*)(smem + SCRo + (((ks*2 + ht)*64 + lane) << 4));
      const int h = ht*16 + rb;
      const float b1v = b1L[h];
      float hs[4], sd[4];
      #pragma unroll
      for (int j = 0; j < 4; ++j){
        const float z = s[j] + b1v;
        const float sg = 1.f / (1.f + __expf(-z));
        hs[j] = z * sg;
        sd[j] = sg * (1.f + z * (1.f - sg));
      }
      #pragma unroll
      for (int j = 0; j < 4; ++j)
        *(uint16_t*)(smem + HQKo + (kg*4 + j)*64 + h*2) = f2bf(hs[j]);
      if (kg >= 2){
        uint2 hv; hv.x = cvtpk(hs[0], hs[1]); hv.y = cvtpk(hs[2], hs[3]);
        *(uint2*)(smem + HKSTo + h*16 + (kg-2)*8) = hv;
        f32x4 sv = {sd[0], sd[1], sd[2], sd[3]};
        *(f32x4*)(smem + SILPo + h*64 + (kg-2)*16) = sv;
      }
    }
    bar();

    // ============ phase B: [y;ck] = [hq;hk] @ W2^T ; y store; g_out ============
    {
      bf16x8 aF = *(const bf16x8*)(smem + HQKo + rb*64 + kg*16);
      #pragma unroll
      for (int u = 0; u < 2; ++u){
        const int mcol = (wid*2 + u)*16 + rb;
        bf16x8 bw = *(const bf16x8*)(smem + W2No + mcol*64 + ((kg ^ (mcol&3)) << 4));
        f32x4 c = mfma16(aF, bw, cz);
        const float b2v = b2L[mcol];
        if (kg < 2){
          #pragma unroll
          for (int j = 0; j < 4; ++j)
            out[(((size_t)(kg*4 + j) << 10) + t)*512 + mcol] = c[j] + b2v;
        } else {
          uint2 vt = *(const uint2*)(smem + VTo + mcol*16 + (kg-2)*8);
          float g0 = (c[0] + b2v - bf2f((uint16_t)vt.x))       * 4.8828125e-4f;
          float g1 = (c[1] + b2v - bf2f((uint16_t)(vt.x>>16))) * 4.8828125e-4f;
          float g2 = (c[2] + b2v - bf2f((uint16_t)vt.y))       * 4.8828125e-4f;
          float g3 = (c[3] + b2v - bf2f((uint16_t)(vt.y>>16))) * 4.8828125e-4f;
          uint2 gp; gp.x = cvtpk(g0, g1); gp.y = cvtpk(g2, g3);
          *(uint2*)(smem + GOTo + mcol*16 + (kg-2)*8) = gp;
          #pragma unroll
          for (int j = 0; j < 4; ++j){
            const int b = kg*4 + j - 8;
            const uint16_t gb = (uint16_t)((j & 1) ? ((j < 2 ? gp.x : gp.y) >> 16)
                                                   : (j < 2 ? gp.x : gp.y));
            *(uint16_t*)(smem + QKLo + (8+b)*1024 + (((mcol>>3) ^ (b&7)) << 4) + ((mcol&7) << 1)) = gb;
          }
        }
      }
    }
    bar();

    // ============ phase C: gpre_raw = g_out @ W2  (16 waves: ht x ks8) ============
    {
      const uint32_t w2row = W2To + (uint32_t)(ht_*16 + rb)*1040;
      f32x4 acc = cz;
      #pragma unroll
      for (int u = 0; u < 2; ++u){
        const int c32 = ks_*2 + u;
        bf16x8 av = (rb < 8) ? *(const bf16x8*)(smem + QKLo + (8+rb)*1024 + (((c32*4 + kg) ^ (rb&7)) << 4)) : zf;
        bf16x8 bv = *(const bf16x8*)(smem + w2row + c32*64 + kg*16);
        acc = mfma16(av, bv, acc);
      }
      *(f32x4*)(smem + SCRo + ((wid*64 + lane) << 4)) = acc;
    }
    bar();

    // ============ Cred: reduce + silu' -> GPT (waves 0-1, kg<2) ============
    if (wid < 2 && kg < 2){
      const int ht = wid;
      f32x4 s = cz;
      #pragma unroll
      for (int ks = 0; ks < 8; ++ks)
        s += *(const f32x4*)(smem + SCRo + (((ks*2 + ht)*64 + lane) << 4));
      const int h = ht*16 + rb;
      f32x4 sp = *(const f32x4*)(smem + SILPo + h*64 + kg*16);
      uint2 w; w.x = cvtpk(s[0]*sp[0], s[1]*sp[1]); w.y = cvtpk(s[2]*sp[2], s[3]*sp[3]);
      *(uint2*)(smem + GPTo + h*16 + kg*8) = w;
    }
    bar();

    // ============ phase D: grads (outer products), updates, restage ============
    {
      bf16x8 hkF[2], gpF[2];
      #pragma unroll
      for (int ht = 0; ht < 2; ++ht){
        const int r0 = ht*16 + rb;
        hkF[ht] = (kg == 0) ? *(const bf16x8*)(smem + HKSTo + r0*16) : zf;
        gpF[ht] = (kg == 0) ? *(const bf16x8*)(smem + GPTo  + r0*16) : zf;
      }
      #pragma unroll
      for (int tt = 0; tt < 2; ++tt){
        const int mA = (wid*2 + tt)*16;
        bf16x8 ktf = (kg == 0) ? *(const bf16x8*)(smem + KTo  + (mA + rb)*16) : zf;
        bf16x8 gof = (kg == 0) ? *(const bf16x8*)(smem + GOTo + (mA + rb)*16) : zf;
        #pragma unroll
        for (int ht = 0; ht < 2; ++ht){
          const int i = tt*2 + ht;
          f32x4 g1 = mfma16(ktf, gpF[ht], cz);   // GW1^T: (m=mA+kg*4+j, h=ht*16+rb)
          f32x4 g2 = mfma16(gof, hkF[ht], cz);   // GW2  : same mapping
          #pragma unroll
          for (int j = 0; j < 4; ++j){
            sm1[i][j] = e_t*sm1[i][j] - th_t*g1[j];
            w1m[i][j] = oma*w1m[i][j] + sm1[i][j];
            sma[i][j] = e_t*sma[i][j] - th_t*g2[j];
            w2a[i][j] = oma*w2a[i][j] + sma[i][j];
          }
          uint2 u1; u1.x = cvtpk(w1m[i][0], w1m[i][1]); u1.y = cvtpk(w1m[i][2], w1m[i][3]);
          *(uint2*)(smem + W1Lo + (ht*16 + rb)*1040 + (mA + kg*4)*2) = u1;
          uint2 u2; u2.x = cvtpk(w2a[i][0], w2a[i][1]); u2.y = cvtpk(w2a[i][2], w2a[i][3]);
          *(uint2*)(smem + W2To + (ht*16 + rb)*1040 + (mA + kg*4)*2) = u2;
        }
      }
      // W2N regen from own-wave W2T columns (bit-identical bf16)
      #pragma unroll
      for (int tt = 0; tt < 2; ++tt){
        const int m2 = (wid*2 + tt)*16 + rb;
        #pragma unroll
        for (int ht = 0; ht < 2; ++ht){
          const uint32_t cb = W2To + (uint32_t)m2*2 + (uint32_t)(ht*16 + kg*4)*1040;
          uint16_t t0 = *(const uint16_t*)(smem + cb);
          uint16_t t1 = *(const uint16_t*)(smem + cb + 1040);
          uint16_t t2 = *(const uint16_t*)(smem + cb + 2080);
          uint16_t t3 = *(const uint16_t*)(smem + cb + 3120);
          uint2 u; u.x = (uint32_t)t0 | ((uint32_t)t1 << 16);
                   u.y = (uint32_t)t2 | ((uint32_t)t3 << 16);
          *(uint2*)(smem + W2No + m2*64 + ((((ht<<1)+(kg>>1)) ^ (m2&3)) << 4) + ((kg&1) << 3)) = u;
        }
      }
      // bias updates
      if (tid < 512){
        uint4 gv = *(const uint4*)(smem + GOTo + tid*16);
        float gb2 = bf2f((uint16_t)gv.x) + bf2f((uint16_t)(gv.x>>16))
                  + bf2f((uint16_t)gv.y) + bf2f((uint16_t)(gv.y>>16))
                  + bf2f((uint16_t)gv.z) + bf2f((uint16_t)(gv.z>>16))
                  + bf2f((uint16_t)gv.w) + bf2f((uint16_t)(gv.w>>16));
        smb2 = e_t*smb2 - th_t*gb2;
        b2m = oma*b2m + smb2;
        b2L[tid] = b2m;
      }
      if (tid < 32){
        uint4 gv = *(const uint4*)(smem + GPTo + tid*16);
        float gb1 = bf2f((uint16_t)gv.x) + bf2f((uint16_t)(gv.x>>16))
                  + bf2f((uint16_t)gv.y) + bf2f((uint16_t)(gv.y>>16))
                  + bf2f((uint16_t)gv.z) + bf2f((uint16_t)(gv.z>>16))
                  + bf2f((uint16_t)gv.w) + bf2f((uint16_t)(gv.w>>16));
        smb1 = e_t*smb1 - th_t*gb1;
        b1m = oma*b1m + smb1;
        b1L[tid] = b1m;
      }
      // restage next step (compiler inserts the precise vmcnt wait for pf*)
      {
        const int b = tid >> 7, m4 = (tid & 127) << 2;
        const uint32_t swz = (((m4>>3) ^ (b&7))<<4) + ((m4&7)<<1);
        *(uint2*)(smem + QKLo + b*1024 + swz)     = pfq;
        *(uint2*)(smem + QKLo + (8+b)*1024 + swz) = pfk;
        if (lane < 32) *(uint4*)(smem + KTo + (wid*32 + lane)*16)      = pf4;
        else           *(uint4*)(smem + VTo + (wid*32 + lane - 32)*16) = pf4;
      }
    }
    bar();
  }
}

// ---------------------------------------------------------------------------
extern "C" void kernel_launch(void* const* d_in, const int* in_sizes, int n_in,
                              void* d_out, int out_size, void* d_ws, size_t ws_size,
                              hipStream_t stream)
{
  const float* x   = (const float*)d_in[0];
  const float* Wk  = (const float*)d_in[1];
  const float* Wv  = (const float*)d_in[2];
  const float* Wq  = (const float*)d_in[3];
  const float* ckw = (const float*)d_in[4];
  const float* ckb = (const float*)d_in[5];
  const float* cvw = (const float*)d_in[6];
  const float* cvb = (const float*)d_in[7];
  const float* cqw = (const float*)d_in[8];
  const float* cqb = (const float*)d_in[9];
  const float* lng = (const float*)d_in[10];
  const float* lnb = (const float*)d_in[11];
  const float* W1g = (const float*)d_in[12];
  const float* b1g = (const float*)d_in[13];
  const float* W2g = (const float*)d_in[14];
  const float* b2g = (const float*)d_in[15];
  const float* aW1 = (const float*)d_in[16];
  const float* ab1 = (const float*)d_in[17];
  const float* aW2 = (const float*)d_in[18];
  const float* ab2 = (const float*)d_in[19];
  const float* tW1 = (const float*)d_in[20];
  const float* tb1 = (const float*)d_in[21];
  const float* tW2 = (const float*)d_in[22];
  const float* tb2 = (const float*)d_in[23];
  const float* eW1 = (const float*)d_in[24];
  const float* eb1 = (const float*)d_in[25];
  const float* eW2 = (const float*)d_in[26];
  const float* eb2 = (const float*)d_in[27];

  char* ws = (char*)d_ws;
  float* gates = (float*)ws;                       // 3*1024 f32
  uint16_t* preK   = (uint16_t*)(ws + 16384);      // 6 x 8MB bf16
  uint16_t* preV   = preK + 4194304;               // reused as postKT after convV
  uint16_t* preQ   = preV + 4194304;
  uint16_t* postK  = preQ + 4194304;               // [S][B][M]
  uint16_t* postQ  = postK + 4194304;              // [S][B][M]
  uint16_t* postVT = postQ + 4194304;              // [S][M][B]
  uint16_t* postKT = preV;                         // [S][M][B] (overlay)

  hipMemsetAsync(gates, 0, 3*1024*sizeof(float), stream);
  nltm_coeff<<<dim3(1024,3), 128, 0, stream>>>(x, aW1,ab1,aW2,ab2, tW1,tb1,tW2,tb2,
                                               eW1,eb1,eW2,eb2, gates);
  nltm_gemm<<<dim3(64,4,3), 256, 0, stream>>>(x, Wk, Wv, Wq, preK, preV, preQ);
  // convV first (frees preV slot), then convK writes postKT into it
  nltm_conv<<<dim3(8192), 512, 0, stream>>>(preV, cvw, cvb, lng, lnb, 0, nullptr, postVT);
  nltm_conv<<<dim3(8192), 512, 0, stream>>>(preK, ckw, ckb, lng, lnb, 1, postK, postKT);
  nltm_conv<<<dim3(8192), 512, 0, stream>>>(preQ, cqw, cqb, lng, lnb, 1, postQ, nullptr);
  nltm_scan<<<dim3(1), dim3(1024), 0, stream>>>(W1g, b1g, W2g, b2g, gates,
                                                postK, postQ, postKT, postVT,
                                                (float*)d_out);
}